// Round 2
// baseline (2221.409 us; speedup 1.0000x reference)
//
#include <hip/hip_runtime.h>
#include <hip/hip_bf16.h>

// NLBlockND (embedded-Gaussian non-local block) for MI355X / gfx950.
// Round 1: fp32 I/O (reference dtype is float32 — round 0's bf16 casts read
// garbage bit-patterns -> NaN). Same tiled-GEMM pipeline, float4 tile loads.
//
// Shapes: N=4, C=512, CI=256, H=W=64 -> L=4096.

#define NB   4
#define CDIM 512
#define CIDIM 256
#define LDIM 4096
#define BN_EPS 1e-5f

// Workspace layout (floats):
//   T: N*CI*L, P: N*CI*L, G: N*CI*L, Y: N*CI*L  (CI*L = 1048576 per batch)
//   F: L*L (per-batch, reused)
//   WY: N*C*L
//   stats: mean[512], inv_std[512]
#define T_OFF  0
#define P_OFF  4194304
#define G_OFF  8388608
#define Y_OFF  12582912
#define F_OFF  16777216
#define WY_OFF 33554432
#define ST_OFF 41943040
// total = 41944064 floats = ~160 MiB

// ---------------------------------------------------------------------------
// Projection: out[o,l] = sum_c W[o,c] * x[n,c,l] + b[o]
// grid: (L/64, CI/64, 3*N), block: 256
// ---------------------------------------------------------------------------
__global__ void proj_kernel(const float* __restrict__ x,
                            const float* __restrict__ gw, const float* __restrict__ gb,
                            const float* __restrict__ tw, const float* __restrict__ tb,
                            const float* __restrict__ pw, const float* __restrict__ pb,
                            float* __restrict__ ws) {
    int which = blockIdx.z % 3;
    int n = blockIdx.z / 3;
    const float* W; const float* B; float* out;
    if (which == 0)      { W = gw; B = gb; out = ws + G_OFF; }
    else if (which == 1) { W = tw; B = tb; out = ws + T_OFF; }
    else                 { W = pw; B = pb; out = ws + P_OFF; }
    out += (size_t)n * CIDIM * LDIM;
    const float* xn = x + (size_t)n * CDIM * LDIM;

    __shared__ float As[16][65];
    __shared__ float Bs[16][65];
    int tid = threadIdx.x;
    int m0 = blockIdx.y * 64, l0 = blockIdx.x * 64;
    float acc[4][4] = {};
    int tm = (tid / 16) * 4, tn = (tid % 16) * 4;
    int am = tid >> 2, ak = (tid & 3) * 4;   // A loader: row am, 4 consecutive k
    int bk = tid >> 4, bl = (tid & 15) * 4;  // B loader: row bk, 4 consecutive l

    for (int k0 = 0; k0 < CDIM; k0 += 16) {
        __syncthreads();
        float4 av = *(const float4*)&W[(m0 + am) * CDIM + k0 + ak];
        As[ak + 0][am] = av.x; As[ak + 1][am] = av.y;
        As[ak + 2][am] = av.z; As[ak + 3][am] = av.w;
        float4 bv = *(const float4*)&xn[(size_t)(k0 + bk) * LDIM + l0 + bl];
        Bs[bk][bl + 0] = bv.x; Bs[bk][bl + 1] = bv.y;
        Bs[bk][bl + 2] = bv.z; Bs[bk][bl + 3] = bv.w;
        __syncthreads();
#pragma unroll
        for (int k = 0; k < 16; k++) {
            float a[4], b[4];
#pragma unroll
            for (int i = 0; i < 4; i++) a[i] = As[k][tm + i];
#pragma unroll
            for (int j = 0; j < 4; j++) b[j] = Bs[k][tn + j];
#pragma unroll
            for (int i = 0; i < 4; i++)
#pragma unroll
                for (int j = 0; j < 4; j++) acc[i][j] += a[i] * b[j];
        }
    }
#pragma unroll
    for (int i = 0; i < 4; i++) {
        float bias = B[m0 + tm + i];
#pragma unroll
        for (int j = 0; j < 4; j++)
            out[(size_t)(m0 + tm + i) * LDIM + l0 + tn + j] = acc[i][j] + bias;
    }
}

// ---------------------------------------------------------------------------
// Scores: f[l,m] = sum_c T[c,l] * P[c,m]    (both (CI, L) row-major)
// grid: (L/64, L/64), block: 256
// ---------------------------------------------------------------------------
__global__ void score_kernel(const float* __restrict__ T, const float* __restrict__ P,
                             float* __restrict__ f) {
    __shared__ float As[16][65];
    __shared__ float Bs[16][65];
    int tid = threadIdx.x;
    int l0 = blockIdx.y * 64, m0 = blockIdx.x * 64;
    float acc[4][4] = {};
    int tm = (tid / 16) * 4, tn = (tid % 16) * 4;
    int lk = tid >> 4, lj = (tid & 15) * 4;

    for (int k0 = 0; k0 < CIDIM; k0 += 16) {
        __syncthreads();
        float4 av = *(const float4*)&T[(size_t)(k0 + lk) * LDIM + l0 + lj];
        As[lk][lj + 0] = av.x; As[lk][lj + 1] = av.y;
        As[lk][lj + 2] = av.z; As[lk][lj + 3] = av.w;
        float4 bv = *(const float4*)&P[(size_t)(k0 + lk) * LDIM + m0 + lj];
        Bs[lk][lj + 0] = bv.x; Bs[lk][lj + 1] = bv.y;
        Bs[lk][lj + 2] = bv.z; Bs[lk][lj + 3] = bv.w;
        __syncthreads();
#pragma unroll
        for (int k = 0; k < 16; k++) {
            float a[4], b[4];
#pragma unroll
            for (int i = 0; i < 4; i++) a[i] = As[k][tm + i];
#pragma unroll
            for (int j = 0; j < 4; j++) b[j] = Bs[k][tn + j];
#pragma unroll
            for (int i = 0; i < 4; i++)
#pragma unroll
                for (int j = 0; j < 4; j++) acc[i][j] += a[i] * b[j];
        }
    }
#pragma unroll
    for (int i = 0; i < 4; i++)
#pragma unroll
        for (int j = 0; j < 4; j++)
            f[(size_t)(l0 + tm + i) * LDIM + m0 + tn + j] = acc[i][j];
}

// ---------------------------------------------------------------------------
// Row softmax over f (L x L), in place. grid: L blocks of 256.
// ---------------------------------------------------------------------------
__global__ void softmax_kernel(float* __restrict__ f) {
    int row = blockIdx.x;
    float* r = f + (size_t)row * LDIM;
    __shared__ float red[256];
    int tid = threadIdx.x;

    float mx = -1e30f;
    for (int i = tid; i < LDIM; i += 256) mx = fmaxf(mx, r[i]);
    red[tid] = mx;
    __syncthreads();
    for (int s = 128; s > 0; s >>= 1) {
        if (tid < s) red[tid] = fmaxf(red[tid], red[tid + s]);
        __syncthreads();
    }
    mx = red[0];
    __syncthreads();

    float sum = 0.f;
    for (int i = tid; i < LDIM; i += 256) {
        float e = __expf(r[i] - mx);
        r[i] = e;
        sum += e;
    }
    red[tid] = sum;
    __syncthreads();
    for (int s = 128; s > 0; s >>= 1) {
        if (tid < s) red[tid] += red[tid + s];
        __syncthreads();
    }
    float inv = 1.0f / red[0];
    for (int i = tid; i < LDIM; i += 256) r[i] *= inv;
}

// ---------------------------------------------------------------------------
// y[c,l] = sum_m G[c,m] * Pm[l,m]   (G: (CI,L) rm, Pm: (L,L) rm) = G * Pm^T
// grid: (L/64, CI/64), block: 256
// ---------------------------------------------------------------------------
__global__ void ygemm_kernel(const float* __restrict__ G, const float* __restrict__ Pm,
                             float* __restrict__ Y) {
    __shared__ float As[16][65];
    __shared__ float Bs[16][65];
    int tid = threadIdx.x;
    int c0 = blockIdx.y * 64, l0 = blockIdx.x * 64;
    float acc[4][4] = {};
    int tm = (tid / 16) * 4, tn = (tid % 16) * 4;
    int ar = tid >> 2, ak = (tid & 3) * 4;  // row ar, 4 consecutive k(m)

    for (int k0 = 0; k0 < LDIM; k0 += 16) {
        __syncthreads();
        float4 av = *(const float4*)&G[(size_t)(c0 + ar) * LDIM + k0 + ak];
        As[ak + 0][ar] = av.x; As[ak + 1][ar] = av.y;
        As[ak + 2][ar] = av.z; As[ak + 3][ar] = av.w;
        float4 bv = *(const float4*)&Pm[(size_t)(l0 + ar) * LDIM + k0 + ak];
        Bs[ak + 0][ar] = bv.x; Bs[ak + 1][ar] = bv.y;
        Bs[ak + 2][ar] = bv.z; Bs[ak + 3][ar] = bv.w;
        __syncthreads();
#pragma unroll
        for (int k = 0; k < 16; k++) {
            float a[4], b[4];
#pragma unroll
            for (int i = 0; i < 4; i++) a[i] = As[k][tm + i];
#pragma unroll
            for (int j = 0; j < 4; j++) b[j] = Bs[k][tn + j];
#pragma unroll
            for (int i = 0; i < 4; i++)
#pragma unroll
                for (int j = 0; j < 4; j++) acc[i][j] += a[i] * b[j];
        }
    }
#pragma unroll
    for (int i = 0; i < 4; i++)
#pragma unroll
        for (int j = 0; j < 4; j++)
            Y[(size_t)(c0 + tm + i) * LDIM + l0 + tn + j] = acc[i][j];
}

// ---------------------------------------------------------------------------
// wy[n,o,l] = sum_c Wz[o,c] * Y[n,c,l] + wzb[o]
// grid: (L/64, C/64, N), block: 256
// ---------------------------------------------------------------------------
__global__ void wz_kernel(const float* __restrict__ Wz, const float* __restrict__ Wzb,
                          const float* __restrict__ Y, float* __restrict__ WY) {
    int n = blockIdx.z;
    const float* yn = Y + (size_t)n * CIDIM * LDIM;
    float* wyn = WY + (size_t)n * CDIM * LDIM;

    __shared__ float As[16][65];
    __shared__ float Bs[16][65];
    int tid = threadIdx.x;
    int m0 = blockIdx.y * 64, l0 = blockIdx.x * 64;
    float acc[4][4] = {};
    int tm = (tid / 16) * 4, tn = (tid % 16) * 4;
    int am = tid >> 2, ak = (tid & 3) * 4;
    int bk = tid >> 4, bl = (tid & 15) * 4;

    for (int k0 = 0; k0 < CIDIM; k0 += 16) {
        __syncthreads();
        float4 av = *(const float4*)&Wz[(m0 + am) * CIDIM + k0 + ak];
        As[ak + 0][am] = av.x; As[ak + 1][am] = av.y;
        As[ak + 2][am] = av.z; As[ak + 3][am] = av.w;
        float4 bv = *(const float4*)&yn[(size_t)(k0 + bk) * LDIM + l0 + bl];
        Bs[bk][bl + 0] = bv.x; Bs[bk][bl + 1] = bv.y;
        Bs[bk][bl + 2] = bv.z; Bs[bk][bl + 3] = bv.w;
        __syncthreads();
#pragma unroll
        for (int k = 0; k < 16; k++) {
            float a[4], b[4];
#pragma unroll
            for (int i = 0; i < 4; i++) a[i] = As[k][tm + i];
#pragma unroll
            for (int j = 0; j < 4; j++) b[j] = Bs[k][tn + j];
#pragma unroll
            for (int i = 0; i < 4; i++)
#pragma unroll
                for (int j = 0; j < 4; j++) acc[i][j] += a[i] * b[j];
        }
    }
#pragma unroll
    for (int i = 0; i < 4; i++) {
        float bias = Wzb[m0 + tm + i];
#pragma unroll
        for (int j = 0; j < 4; j++)
            wyn[(size_t)(m0 + tm + i) * LDIM + l0 + tn + j] = acc[i][j] + bias;
    }
}

// ---------------------------------------------------------------------------
// BN stats: per channel o over (N, L): mean + inv_std. grid: C blocks of 256.
// ---------------------------------------------------------------------------
__global__ void bn_stats_kernel(const float* __restrict__ WY, float* __restrict__ stats) {
    int o = blockIdx.x;
    int tid = threadIdx.x;
    __shared__ float rs[256];
    __shared__ float rs2[256];
    float s = 0.f, s2 = 0.f;
    for (int n = 0; n < NB; n++) {
        const float* p = WY + (size_t)(n * CDIM + o) * LDIM;
        for (int i = tid; i < LDIM; i += 256) {
            float v = p[i];
            s += v;
            s2 += v * v;
        }
    }
    rs[tid] = s; rs2[tid] = s2;
    __syncthreads();
    for (int st = 128; st > 0; st >>= 1) {
        if (tid < st) { rs[tid] += rs[tid + st]; rs2[tid] += rs2[tid + st]; }
        __syncthreads();
    }
    if (tid == 0) {
        const float cnt = (float)(NB * LDIM);
        float mean = rs[0] / cnt;
        float var = rs2[0] / cnt - mean * mean;
        stats[o] = mean;
        stats[CDIM + o] = rsqrtf(var + BN_EPS);
    }
}

// ---------------------------------------------------------------------------
// Apply BN + residual. grid-stride over N*C*L.
// ---------------------------------------------------------------------------
__global__ void bn_apply_kernel(const float* __restrict__ WY, const float* __restrict__ stats,
                                const float* __restrict__ x,
                                const float* __restrict__ gamma, const float* __restrict__ beta,
                                float* __restrict__ out) {
    int idx = blockIdx.x * 256 + threadIdx.x;
    const int total = NB * CDIM * LDIM;
    if (idx >= total) return;
    int o = (idx >> 12) & (CDIM - 1);  // (idx / L) % C  (L=4096, C=512, pow2)
    float m = stats[o];
    float is = stats[CDIM + o];
    float v = (WY[idx] - m) * is * gamma[o] + beta[o] + x[idx];
    out[idx] = v;
}

// ---------------------------------------------------------------------------
extern "C" void kernel_launch(void* const* d_in, const int* in_sizes, int n_in,
                              void* d_out, int out_size, void* d_ws, size_t ws_size,
                              hipStream_t stream) {
    const float* x  = (const float*)d_in[0];
    const float* gw = (const float*)d_in[1];
    const float* gb = (const float*)d_in[2];
    const float* tw = (const float*)d_in[3];
    const float* tb = (const float*)d_in[4];
    const float* pw = (const float*)d_in[5];
    const float* pb = (const float*)d_in[6];
    const float* zw = (const float*)d_in[7];
    const float* zb = (const float*)d_in[8];
    const float* bng = (const float*)d_in[9];
    const float* bnb = (const float*)d_in[10];
    float* out = (float*)d_out;
    float* ws = (float*)d_ws;

    // 1) projections: g, theta, phi  (fp32 into ws)
    proj_kernel<<<dim3(LDIM / 64, CIDIM / 64, 3 * NB), 256, 0, stream>>>(
        x, gw, gb, tw, tb, pw, pb, ws);

    // 2) per-batch attention (f buffer reused across batches)
    for (int n = 0; n < NB; n++) {
        const float* tn = ws + T_OFF + (size_t)n * CIDIM * LDIM;
        const float* pn = ws + P_OFF + (size_t)n * CIDIM * LDIM;
        const float* gn = ws + G_OFF + (size_t)n * CIDIM * LDIM;
        float* yn = ws + Y_OFF + (size_t)n * CIDIM * LDIM;
        float* f  = ws + F_OFF;

        score_kernel<<<dim3(LDIM / 64, LDIM / 64), 256, 0, stream>>>(tn, pn, f);
        softmax_kernel<<<dim3(LDIM), 256, 0, stream>>>(f);
        ygemm_kernel<<<dim3(LDIM / 64, CIDIM / 64), 256, 0, stream>>>(gn, f, yn);
    }

    // 3) output projection
    wz_kernel<<<dim3(LDIM / 64, CDIM / 64, NB), 256, 0, stream>>>(
        zw, zb, ws + Y_OFF, ws + WY_OFF);

    // 4) batch-norm stats + apply + residual
    bn_stats_kernel<<<dim3(CDIM), 256, 0, stream>>>(ws + WY_OFF, ws + ST_OFF);

    const int total = NB * CDIM * LDIM;
    bn_apply_kernel<<<dim3((total + 255) / 256), 256, 0, stream>>>(
        ws + WY_OFF, ws + ST_OFF, x, bng, bnb, out);
}

// Round 3
// 678.246 us; speedup vs baseline: 3.2752x; 3.2752x over previous
//
#include <hip/hip_runtime.h>
#include <hip/hip_bf16.h>

// NLBlockND (embedded non-local block), MI355X/gfx950.
// Round 2: all GEMM stages via bf16 MFMA 16x16x32, m97-style 128x128 tiles
// with global_load_lds(16B) staging. fp32 scores + softmax, bf16 elsewhere.
// Shapes: N=4, C=512, CI=256, L=4096.

#define NB    4
#define CDIM  512
#define CIDIM 256
#define LDIM  4096
#define BN_EPS 1e-5f

typedef unsigned short u16;
typedef __attribute__((ext_vector_type(8))) short short8;  // 8 bf16 (4 VGPRs)
typedef __attribute__((ext_vector_type(4))) float f32x4;   // MFMA C/D
typedef __attribute__((ext_vector_type(4))) unsigned short u16x4;

// Workspace layout (float offsets). Regions overlap where lifetimes permit:
//   F (scores fp32, per-batch reuse) also hosts xT (bf16) which dies after proj.
//   PM (attn probs bf16, per-batch) is later overwritten by WY (fp32).
#define F_OFF   0                    // 16,777,216 floats (also xT: 8.4M bf16)
#define PM_OFF  16777216             //  8,388,608 floats (Pm bf16 / WY fp32)
#define TH_OFF  25165824             //  2,097,152 floats (thetaT bf16, (N,L,CI))
#define PH_OFF  27262976             //  2,097,152
#define G_OFF   29360128             //  2,097,152 (g bf16, (N,CI,L))
#define Y_OFF   31457280             //  2,097,152 (yT bf16, (N,L,CI))
#define WTS_OFF 33554432             //    262,144 floats = 524,288 bf16 weights
#define ST_OFF  33816576             //      1,024
// total 33,817,600 floats = 135.3 MB

__device__ __forceinline__ u16 f2b(float f) {  // fp32 -> bf16 RNE
    union { float f; unsigned u; } v; v.f = f;
    return (u16)((v.u + 0x7FFFu + ((v.u >> 16) & 1u)) >> 16);
}

__device__ __forceinline__ void gl_lds16(const u16* g, u16* l) {
    __builtin_amdgcn_global_load_lds(
        (const __attribute__((address_space(1))) void*)g,
        (__attribute__((address_space(3))) void*)l, 16, 0, 0);
}

// ---------------------------------------------------------------------------
// x (N,C,L) fp32 -> xT (N,L,C) bf16.  32x32 LDS tiles.
// ---------------------------------------------------------------------------
__global__ void transpose_x(const float* __restrict__ x, u16* __restrict__ xt) {
    __shared__ float tile[32][33];
    int n = blockIdx.z;
    int l0 = blockIdx.x * 32, c0 = blockIdx.y * 32;
    const float* xn = x + (size_t)n * CDIM * LDIM;
    u16* xtn = xt + (size_t)n * LDIM * CDIM;
    int tx = threadIdx.x, ty = threadIdx.y;  // (32, 8)
#pragma unroll
    for (int k = 0; k < 4; k++)
        tile[ty + 8 * k][tx] = xn[(size_t)(c0 + ty + 8 * k) * LDIM + l0 + tx];
    __syncthreads();
#pragma unroll
    for (int k = 0; k < 4; k++)
        xtn[(size_t)(l0 + ty + 8 * k) * CDIM + c0 + tx] = f2b(tile[tx][ty + 8 * k]);
}

// ---------------------------------------------------------------------------
// Cast the 4 weight matrices (each 131072 fp32) to bf16, concatenated.
// ---------------------------------------------------------------------------
__global__ void cast_w(const float* __restrict__ gw, const float* __restrict__ tw,
                       const float* __restrict__ pw, const float* __restrict__ zw,
                       u16* __restrict__ out) {
    int idx = blockIdx.x * 256 + threadIdx.x;
    if (idx >= 4 * 131072) return;
    int seg = idx >> 17, off = idx & 131071;
    const float* s = (seg == 0) ? gw : (seg == 1) ? tw : (seg == 2) ? pw : zw;
    out[idx] = f2b(s[off]);
}

// ---------------------------------------------------------------------------
// NT-GEMM: D[m][n] = sum_k A[m][k]*B[n][k] (+bias), A:MxK bf16, B:NxK bf16.
// 128x128 tile, BK=32, 256 threads (4 waves, 2x2), 16x16x32 bf16 MFMA.
// BIAS_MODE: 0 none, 1 bias[m], 2 bias[n].  OUT_BF16: store bf16 else fp32.
// grid: (N/128, M/128, batches)
// ---------------------------------------------------------------------------
template <int BIAS_MODE, bool OUT_BF16>
__global__ __launch_bounds__(256)
void gemm_nt(const u16* __restrict__ A, const u16* __restrict__ B,
             void* __restrict__ Dv, const float* __restrict__ bias,
             int K, int ldd, long batchA, long batchB, long batchD) {
    __shared__ __align__(16) u16 As[128 * 32];
    __shared__ __align__(16) u16 Bs[128 * 32];
    int z = blockIdx.z;
    A += (size_t)z * batchA;
    B += (size_t)z * batchB;

    int tid = threadIdx.x, lane = tid & 63, wave = tid >> 6;
    int n0 = blockIdx.x * 128, m0 = blockIdx.y * 128;
    int wr = wave >> 1, wc = wave & 1;

    f32x4 acc[4][4];
#pragma unroll
    for (int i = 0; i < 4; i++)
#pragma unroll
        for (int j = 0; j < 4; j++) acc[i][j] = (f32x4){0.f, 0.f, 0.f, 0.f};

    // staging: per wave, instruction q in {0,1} fills rows [q*64+wave*16, +16)
    int sr = wave * 16 + (lane >> 2);
    int sk = (lane & 3) * 8;
    const u16* Ag0 = A + (size_t)(m0 + sr) * K + sk;
    const u16* Ag1 = A + (size_t)(m0 + 64 + sr) * K + sk;
    const u16* Bg0 = B + (size_t)(n0 + sr) * K + sk;
    const u16* Bg1 = B + (size_t)(n0 + 64 + sr) * K + sk;
    u16* Al0 = &As[(wave * 16) * 32];        // wave-uniform LDS base, +lane*16B
    u16* Al1 = &As[(64 + wave * 16) * 32];
    u16* Bl0 = &Bs[(wave * 16) * 32];
    u16* Bl1 = &Bs[(64 + wave * 16) * 32];

    int koff = (lane >> 4) * 8;
    int ra = (wr * 64 + (lane & 15)) * 32 + koff;
    int rb = (wc * 64 + (lane & 15)) * 32 + koff;

    for (int k0 = 0; k0 < K; k0 += 32) {
        __syncthreads();
        gl_lds16(Ag0 + k0, Al0);
        gl_lds16(Ag1 + k0, Al1);
        gl_lds16(Bg0 + k0, Bl0);
        gl_lds16(Bg1 + k0, Bl1);
        __syncthreads();

        short8 af[4], bf[4];
#pragma unroll
        for (int mt = 0; mt < 4; mt++) af[mt] = *(const short8*)&As[ra + mt * 16 * 32];
#pragma unroll
        for (int nt = 0; nt < 4; nt++) bf[nt] = *(const short8*)&Bs[rb + nt * 16 * 32];
#pragma unroll
        for (int mt = 0; mt < 4; mt++)
#pragma unroll
            for (int nt = 0; nt < 4; nt++)
                acc[mt][nt] = __builtin_amdgcn_mfma_f32_16x16x32_bf16(
                    af[mt], bf[nt], acc[mt][nt], 0, 0, 0);
    }

    // epilogue: C/D layout col=lane&15, row=(lane>>4)*4+reg
#pragma unroll
    for (int mt = 0; mt < 4; mt++) {
        int mg = m0 + wr * 64 + mt * 16 + (lane >> 4) * 4;
#pragma unroll
        for (int nt = 0; nt < 4; nt++) {
            int ng = n0 + wc * 64 + nt * 16 + (lane & 15);
#pragma unroll
            for (int r = 0; r < 4; r++) {
                float v = acc[mt][nt][r];
                if (BIAS_MODE == 1) v += bias[mg + r];
                if (BIAS_MODE == 2) v += bias[ng];
                if (OUT_BF16) {
                    u16* D = (u16*)Dv + (size_t)z * batchD;
                    D[(size_t)(mg + r) * ldd + ng] = f2b(v);
                } else {
                    float* D = (float*)Dv + (size_t)z * batchD;
                    D[(size_t)(mg + r) * ldd + ng] = v;
                }
            }
        }
    }
}

// ---------------------------------------------------------------------------
// Row softmax: f (L x L fp32) -> pm (L x L bf16). One block per row.
// Row cached in registers (16 floats/thread) -> single global read.
// ---------------------------------------------------------------------------
__global__ void softmax_kernel(const float* __restrict__ f, u16* __restrict__ pm) {
    int row = blockIdx.x, tid = threadIdx.x, lane = tid & 63, wave = tid >> 6;
    const float4* fr = (const float4*)(f + (size_t)row * LDIM);
    float4 v[4];
    float mx = -1e30f;
#pragma unroll
    for (int i = 0; i < 4; i++) {
        v[i] = fr[i * 256 + tid];
        mx = fmaxf(mx, fmaxf(fmaxf(v[i].x, v[i].y), fmaxf(v[i].z, v[i].w)));
    }
    for (int o = 32; o > 0; o >>= 1) mx = fmaxf(mx, __shfl_xor(mx, o, 64));
    __shared__ float red[8];
    if (lane == 0) red[wave] = mx;
    __syncthreads();
    mx = fmaxf(fmaxf(red[0], red[1]), fmaxf(red[2], red[3]));

    float sum = 0.f;
#pragma unroll
    for (int i = 0; i < 4; i++) {
        v[i].x = __expf(v[i].x - mx);
        v[i].y = __expf(v[i].y - mx);
        v[i].z = __expf(v[i].z - mx);
        v[i].w = __expf(v[i].w - mx);
        sum += v[i].x + v[i].y + v[i].z + v[i].w;
    }
    for (int o = 32; o > 0; o >>= 1) sum += __shfl_xor(sum, o, 64);
    if (lane == 0) red[4 + wave] = sum;
    __syncthreads();
    float inv = 1.f / (red[4] + red[5] + red[6] + red[7]);

    u16x4* pr = (u16x4*)(pm + (size_t)row * LDIM);
#pragma unroll
    for (int i = 0; i < 4; i++) {
        u16x4 o4;
        o4.x = f2b(v[i].x * inv);
        o4.y = f2b(v[i].y * inv);
        o4.z = f2b(v[i].z * inv);
        o4.w = f2b(v[i].w * inv);
        pr[i * 256 + tid] = o4;
    }
}

// ---------------------------------------------------------------------------
// BN stats per channel o over (N, L). WY layout (N, C, L) fp32.
// ---------------------------------------------------------------------------
__global__ void bn_stats_kernel(const float* __restrict__ WY, float* __restrict__ stats) {
    int o = blockIdx.x, tid = threadIdx.x, lane = tid & 63, wave = tid >> 6;
    float s = 0.f, s2 = 0.f;
    for (int n = 0; n < NB; n++) {
        const float4* p = (const float4*)(WY + (size_t)(n * CDIM + o) * LDIM);
        for (int i = tid; i < LDIM / 4; i += 256) {
            float4 v = p[i];
            s += v.x + v.y + v.z + v.w;
            s2 += v.x * v.x + v.y * v.y + v.z * v.z + v.w * v.w;
        }
    }
    for (int o2 = 32; o2 > 0; o2 >>= 1) {
        s += __shfl_xor(s, o2, 64);
        s2 += __shfl_xor(s2, o2, 64);
    }
    __shared__ float rs[4], rs2[4];
    if (lane == 0) { rs[wave] = s; rs2[wave] = s2; }
    __syncthreads();
    if (tid == 0) {
        float S = rs[0] + rs[1] + rs[2] + rs[3];
        float S2 = rs2[0] + rs2[1] + rs2[2] + rs2[3];
        const float cnt = (float)(NB * LDIM);
        float mean = S / cnt;
        float var = S2 / cnt - mean * mean;
        stats[o] = mean;
        stats[CDIM + o] = rsqrtf(var + BN_EPS);
    }
}

// ---------------------------------------------------------------------------
// BN apply + residual, float4 vectorized. total/4 threads.
// ---------------------------------------------------------------------------
__global__ void bn_apply_kernel(const float* __restrict__ WY, const float* __restrict__ stats,
                                const float* __restrict__ x,
                                const float* __restrict__ gamma, const float* __restrict__ beta,
                                float* __restrict__ out) {
    int i4 = blockIdx.x * 256 + threadIdx.x;  // < N*C*L/4
    int o = (i4 >> 10) & (CDIM - 1);
    float m = stats[o], is = stats[CDIM + o];
    float ga = gamma[o], be = beta[o];
    float4 w = ((const float4*)WY)[i4];
    float4 xv = ((const float4*)x)[i4];
    float4 r;
    r.x = (w.x - m) * is * ga + be + xv.x;
    r.y = (w.y - m) * is * ga + be + xv.y;
    r.z = (w.z - m) * is * ga + be + xv.z;
    r.w = (w.w - m) * is * ga + be + xv.w;
    ((float4*)out)[i4] = r;
}

// ---------------------------------------------------------------------------
extern "C" void kernel_launch(void* const* d_in, const int* in_sizes, int n_in,
                              void* d_out, int out_size, void* d_ws, size_t ws_size,
                              hipStream_t stream) {
    const float* x   = (const float*)d_in[0];
    const float* gw  = (const float*)d_in[1];
    const float* gb  = (const float*)d_in[2];
    const float* tw  = (const float*)d_in[3];
    const float* tb  = (const float*)d_in[4];
    const float* pw  = (const float*)d_in[5];
    const float* pb  = (const float*)d_in[6];
    const float* zw  = (const float*)d_in[7];
    const float* zb  = (const float*)d_in[8];
    const float* bng = (const float*)d_in[9];
    const float* bnb = (const float*)d_in[10];
    float* out = (float*)d_out;
    float* ws  = (float*)d_ws;

    float* F  = ws + F_OFF;
    u16*   xT = (u16*)(ws + F_OFF);      // xT dies before F is written
    u16*   Pm = (u16*)(ws + PM_OFF);
    float* WY = ws + PM_OFF;             // WY written after last Pm read
    u16*   TH = (u16*)(ws + TH_OFF);
    u16*   PH = (u16*)(ws + PH_OFF);
    u16*   G  = (u16*)(ws + G_OFF);
    u16*   Y  = (u16*)(ws + Y_OFF);
    u16*   WB = (u16*)(ws + WTS_OFF);    // [gw | tw | pw | zw] bf16
    float* ST = ws + ST_OFF;

    const long LC  = (long)LDIM * CDIM;    // 2,097,152 (xT batch, u16)
    const long LCI = (long)LDIM * CIDIM;   // 1,048,576
    const long CL  = (long)CDIM * LDIM;    // 2,097,152 (WY batch, fp32)

    transpose_x<<<dim3(LDIM / 32, CDIM / 32, NB), dim3(32, 8), 0, stream>>>(x, xT);
    cast_w<<<2048, 256, 0, stream>>>(gw, tw, pw, zw, WB);

    // thetaT (N,L,CI) = xT(L,C) x tw(CI,C)^T   [bias per-n]
    gemm_nt<2, true><<<dim3(2, 32, NB), 256, 0, stream>>>(
        xT, WB + 131072, TH, tb, CDIM, CIDIM, LC, 0, LCI);
    // phiT
    gemm_nt<2, true><<<dim3(2, 32, NB), 256, 0, stream>>>(
        xT, WB + 262144, PH, pb, CDIM, CIDIM, LC, 0, LCI);
    // g (N,CI,L) = gw(CI,C) x xT(L,C)^T        [bias per-m]
    gemm_nt<1, true><<<dim3(32, 2, NB), 256, 0, stream>>>(
        WB, xT, G, gb, CDIM, LDIM, 0, LC, LCI);

    for (int n = 0; n < NB; n++) {
        // f (L,L) fp32 = thetaT x phiT^T
        gemm_nt<0, false><<<dim3(32, 32, 1), 256, 0, stream>>>(
            TH + (size_t)n * LCI, PH + (size_t)n * LCI, (void*)F, nullptr,
            CIDIM, LDIM, 0, 0, 0);
        softmax_kernel<<<dim3(LDIM), 256, 0, stream>>>(F, Pm);
        // yT (L,CI) = Pm(L,L) x g(CI,L)^T
        gemm_nt<0, true><<<dim3(2, 32, 1), 256, 0, stream>>>(
            Pm, G + (size_t)n * LCI, Y + (size_t)n * LCI, nullptr,
            LDIM, CIDIM, 0, 0, 0);
    }

    // WY (N,C,L) fp32 = zw(C,CI) x yT(L,CI)^T  [bias per-m]
    gemm_nt<1, false><<<dim3(32, 4, NB), 256, 0, stream>>>(
        WB + 393216, Y, (void*)WY, zb, CIDIM, LDIM, 0, LCI, CL);

    bn_stats_kernel<<<dim3(CDIM), 256, 0, stream>>>(WY, ST);
    bn_apply_kernel<<<dim3(NB * CDIM * LDIM / 4 / 256), 256, 0, stream>>>(
        WY, ST, x, bng, bnb, out);
}

// Round 4
// 438.818 us; speedup vs baseline: 5.0623x; 1.5456x over previous
//
#include <hip/hip_runtime.h>
#include <hip/hip_bf16.h>

// NLBlockND (embedded non-local block), MI355X/gfx950.
// Round 4: occupancy fixes. Split-K x8 on the attn@g GEMM (was 64 blocks,
// 2.7% occupancy, 95us x4 = 380us of 678us). Merged theta+phi projection.
// General lda/ldb in gemm_nt (batch strides double as split-K offsets).
// Shapes: N=4, C=512, CI=256, L=4096.

#define NB    4
#define CDIM  512
#define CIDIM 256
#define LDIM  4096
#define BN_EPS 1e-5f

typedef unsigned short u16;
typedef __attribute__((ext_vector_type(8))) short short8;  // 8 bf16 (4 VGPRs)
typedef __attribute__((ext_vector_type(4))) float f32x4;   // MFMA C/D
typedef __attribute__((ext_vector_type(4))) unsigned short u16x4;

// Workspace layout (float offsets), regions overlap where lifetimes permit:
//   F (fp32 scores, per-batch) hosts xT (bf16, dies after proj) and, in its
//   upper half, the split-K partials (written only after softmax reads F).
//   PM (bf16 probs, per-batch) is later overwritten by WY (fp32).
#define F_OFF     0                  // 16,777,216 floats
#define SPLIT_OFF 8388608            //  8 x 1,048,576 fp32 partials (in F)
#define PM_OFF    16777216           //  8,388,608 floats (Pm bf16 / WY fp32)
#define THPH_OFF  25165824           //  4,194,304 floats (N,L,512 bf16: [th|ph])
#define G_OFF     29360128           //  2,097,152 floats (g bf16, (N,CI,L))
#define Y_OFF     31457280           //  2,097,152 floats (yT bf16, (N,L,CI))
#define WTS_OFF   33554432           //    262,144 floats = 524,288 bf16 weights
#define BIAS2_OFF 33816576           //        512 floats ([tb|pb])
#define ST_OFF    33817088           //      1,024 floats
// total 33,818,112 floats = 135.3 MB

__device__ __forceinline__ u16 f2b(float f) {  // fp32 -> bf16 RNE
    union { float f; unsigned u; } v; v.f = f;
    return (u16)((v.u + 0x7FFFu + ((v.u >> 16) & 1u)) >> 16);
}

__device__ __forceinline__ void gl_lds16(const u16* g, u16* l) {
    __builtin_amdgcn_global_load_lds(
        (const __attribute__((address_space(1))) void*)g,
        (__attribute__((address_space(3))) void*)l, 16, 0, 0);
}

// ---------------------------------------------------------------------------
// x (N,C,L) fp32 -> xT (N,L,C) bf16.  32x32 LDS tiles.
// ---------------------------------------------------------------------------
__global__ void transpose_x(const float* __restrict__ x, u16* __restrict__ xt) {
    __shared__ float tile[32][33];
    int n = blockIdx.z;
    int l0 = blockIdx.x * 32, c0 = blockIdx.y * 32;
    const float* xn = x + (size_t)n * CDIM * LDIM;
    u16* xtn = xt + (size_t)n * LDIM * CDIM;
    int tx = threadIdx.x, ty = threadIdx.y;  // (32, 8)
#pragma unroll
    for (int k = 0; k < 4; k++)
        tile[ty + 8 * k][tx] = xn[(size_t)(c0 + ty + 8 * k) * LDIM + l0 + tx];
    __syncthreads();
#pragma unroll
    for (int k = 0; k < 4; k++)
        xtn[(size_t)(l0 + ty + 8 * k) * CDIM + c0 + tx] = f2b(tile[tx][ty + 8 * k]);
}

// ---------------------------------------------------------------------------
// Cast the 4 weight matrices (each 131072 fp32) to bf16, concatenated.
// ---------------------------------------------------------------------------
__global__ void cast_w(const float* __restrict__ gw, const float* __restrict__ tw,
                       const float* __restrict__ pw, const float* __restrict__ zw,
                       u16* __restrict__ out) {
    int idx = blockIdx.x * 256 + threadIdx.x;
    if (idx >= 4 * 131072) return;
    int seg = idx >> 17, off = idx & 131071;
    const float* s = (seg == 0) ? gw : (seg == 1) ? tw : (seg == 2) ? pw : zw;
    out[idx] = f2b(s[off]);
}

__global__ void concat_bias(const float* __restrict__ tb, const float* __restrict__ pb,
                            float* __restrict__ out) {
    int i = blockIdx.x * 256 + threadIdx.x;
    if (i < 256) out[i] = tb[i];
    else if (i < 512) out[i] = pb[i - 256];
}

// ---------------------------------------------------------------------------
// NT-GEMM: D[m][n] = sum_k A[m][k]*B[n][k] (+bias), A,B bf16 with row strides
// lda/ldb. 128x128 tile, BK=32, 256 threads (4 waves 2x2), 16x16x32 bf16 MFMA.
// Batch strides (elements) allow both real batching and split-K offsets.
// BIAS_MODE: 0 none, 1 bias[m], 2 bias[n].  OUT_BF16: store bf16 else fp32.
// grid: (N/128, M/128, batches)
// ---------------------------------------------------------------------------
template <int BIAS_MODE, bool OUT_BF16>
__global__ __launch_bounds__(256)
void gemm_nt(const u16* __restrict__ A, const u16* __restrict__ B,
             void* __restrict__ Dv, const float* __restrict__ bias,
             int K, int lda, int ldb, int ldd,
             long batchA, long batchB, long batchD) {
    __shared__ __align__(16) u16 As[128 * 32];
    __shared__ __align__(16) u16 Bs[128 * 32];
    int z = blockIdx.z;
    A += (size_t)z * batchA;
    B += (size_t)z * batchB;

    int tid = threadIdx.x, lane = tid & 63, wave = tid >> 6;
    int n0 = blockIdx.x * 128, m0 = blockIdx.y * 128;
    int wr = wave >> 1, wc = wave & 1;

    f32x4 acc[4][4];
#pragma unroll
    for (int i = 0; i < 4; i++)
#pragma unroll
        for (int j = 0; j < 4; j++) acc[i][j] = (f32x4){0.f, 0.f, 0.f, 0.f};

    int sr = wave * 16 + (lane >> 2);
    int sk = (lane & 3) * 8;
    const u16* Ag0 = A + (size_t)(m0 + sr) * lda + sk;
    const u16* Ag1 = A + (size_t)(m0 + 64 + sr) * lda + sk;
    const u16* Bg0 = B + (size_t)(n0 + sr) * ldb + sk;
    const u16* Bg1 = B + (size_t)(n0 + 64 + sr) * ldb + sk;
    u16* Al0 = &As[(wave * 16) * 32];        // wave-uniform LDS base, +lane*16B
    u16* Al1 = &As[(64 + wave * 16) * 32];
    u16* Bl0 = &Bs[(wave * 16) * 32];
    u16* Bl1 = &Bs[(64 + wave * 16) * 32];

    int koff = (lane >> 4) * 8;
    int ra = (wr * 64 + (lane & 15)) * 32 + koff;
    int rb = (wc * 64 + (lane & 15)) * 32 + koff;

    for (int k0 = 0; k0 < K; k0 += 32) {
        __syncthreads();
        gl_lds16(Ag0 + k0, Al0);
        gl_lds16(Ag1 + k0, Al1);
        gl_lds16(Bg0 + k0, Bl0);
        gl_lds16(Bg1 + k0, Bl1);
        __syncthreads();

        short8 af[4], bf[4];
#pragma unroll
        for (int mt = 0; mt < 4; mt++) af[mt] = *(const short8*)&As[ra + mt * 16 * 32];
#pragma unroll
        for (int nt = 0; nt < 4; nt++) bf[nt] = *(const short8*)&Bs[rb + nt * 16 * 32];
#pragma unroll
        for (int mt = 0; mt < 4; mt++)
#pragma unroll
            for (int nt = 0; nt < 4; nt++)
                acc[mt][nt] = __builtin_amdgcn_mfma_f32_16x16x32_bf16(
                    af[mt], bf[nt], acc[mt][nt], 0, 0, 0);
    }

    // epilogue: C/D layout col=lane&15, row=(lane>>4)*4+reg
#pragma unroll
    for (int mt = 0; mt < 4; mt++) {
        int mg = m0 + wr * 64 + mt * 16 + (lane >> 4) * 4;
#pragma unroll
        for (int nt = 0; nt < 4; nt++) {
            int ng = n0 + wc * 64 + nt * 16 + (lane & 15);
#pragma unroll
            for (int r = 0; r < 4; r++) {
                float v = acc[mt][nt][r];
                if (BIAS_MODE == 1) v += bias[mg + r];
                if (BIAS_MODE == 2) v += bias[ng];
                if (OUT_BF16) {
                    u16* D = (u16*)Dv + (size_t)z * batchD;
                    D[(size_t)(mg + r) * ldd + ng] = f2b(v);
                } else {
                    float* D = (float*)Dv + (size_t)z * batchD;
                    D[(size_t)(mg + r) * ldd + ng] = v;
                }
            }
        }
    }
}

// ---------------------------------------------------------------------------
// Row softmax: f (L x L fp32) -> pm (L x L bf16). One block per row.
// ---------------------------------------------------------------------------
__global__ void softmax_kernel(const float* __restrict__ f, u16* __restrict__ pm) {
    int row = blockIdx.x, tid = threadIdx.x, lane = tid & 63, wave = tid >> 6;
    const float4* fr = (const float4*)(f + (size_t)row * LDIM);
    float4 v[4];
    float mx = -1e30f;
#pragma unroll
    for (int i = 0; i < 4; i++) {
        v[i] = fr[i * 256 + tid];
        mx = fmaxf(mx, fmaxf(fmaxf(v[i].x, v[i].y), fmaxf(v[i].z, v[i].w)));
    }
    for (int o = 32; o > 0; o >>= 1) mx = fmaxf(mx, __shfl_xor(mx, o, 64));
    __shared__ float red[8];
    if (lane == 0) red[wave] = mx;
    __syncthreads();
    mx = fmaxf(fmaxf(red[0], red[1]), fmaxf(red[2], red[3]));

    float sum = 0.f;
#pragma unroll
    for (int i = 0; i < 4; i++) {
        v[i].x = __expf(v[i].x - mx);
        v[i].y = __expf(v[i].y - mx);
        v[i].z = __expf(v[i].z - mx);
        v[i].w = __expf(v[i].w - mx);
        sum += v[i].x + v[i].y + v[i].z + v[i].w;
    }
    for (int o = 32; o > 0; o >>= 1) sum += __shfl_xor(sum, o, 64);
    if (lane == 0) red[4 + wave] = sum;
    __syncthreads();
    float inv = 1.f / (red[4] + red[5] + red[6] + red[7]);

    u16x4* pr = (u16x4*)(pm + (size_t)row * LDIM);
#pragma unroll
    for (int i = 0; i < 4; i++) {
        u16x4 o4;
        o4.x = f2b(v[i].x * inv);
        o4.y = f2b(v[i].y * inv);
        o4.z = f2b(v[i].z * inv);
        o4.w = f2b(v[i].w * inv);
        pr[i * 256 + tid] = o4;
    }
}

// ---------------------------------------------------------------------------
// Split-K reduce: Y[i] = bf16( sum_{s<8} P[s*LCI + i] ).  float4 lanes.
// grid: LCI/4/256 = 1024 blocks.
// ---------------------------------------------------------------------------
__global__ void reduce_y(const float* __restrict__ P, u16* __restrict__ Y) {
    const int LCI4 = LDIM * CIDIM / 4;
    int i4 = blockIdx.x * 256 + threadIdx.x;
    float4 s = ((const float4*)P)[i4];
#pragma unroll
    for (int sp = 1; sp < 8; sp++) {
        float4 v = ((const float4*)P)[sp * LCI4 + i4];
        s.x += v.x; s.y += v.y; s.z += v.z; s.w += v.w;
    }
    u16x4 o;
    o.x = f2b(s.x); o.y = f2b(s.y); o.z = f2b(s.z); o.w = f2b(s.w);
    ((u16x4*)Y)[i4] = o;
}

// ---------------------------------------------------------------------------
// BN stats per channel o over (N, L). WY layout (N, C, L) fp32.
// ---------------------------------------------------------------------------
__global__ void bn_stats_kernel(const float* __restrict__ WY, float* __restrict__ stats) {
    int o = blockIdx.x, tid = threadIdx.x, lane = tid & 63, wave = tid >> 6;
    float s = 0.f, s2 = 0.f;
    for (int n = 0; n < NB; n++) {
        const float4* p = (const float4*)(WY + (size_t)(n * CDIM + o) * LDIM);
        for (int i = tid; i < LDIM / 4; i += 256) {
            float4 v = p[i];
            s += v.x + v.y + v.z + v.w;
            s2 += v.x * v.x + v.y * v.y + v.z * v.z + v.w * v.w;
        }
    }
    for (int o2 = 32; o2 > 0; o2 >>= 1) {
        s += __shfl_xor(s, o2, 64);
        s2 += __shfl_xor(s2, o2, 64);
    }
    __shared__ float rs[4], rs2[4];
    if (lane == 0) { rs[wave] = s; rs2[wave] = s2; }
    __syncthreads();
    if (tid == 0) {
        float S = rs[0] + rs[1] + rs[2] + rs[3];
        float S2 = rs2[0] + rs2[1] + rs2[2] + rs2[3];
        const float cnt = (float)(NB * LDIM);
        float mean = S / cnt;
        float var = S2 / cnt - mean * mean;
        stats[o] = mean;
        stats[CDIM + o] = rsqrtf(var + BN_EPS);
    }
}

// ---------------------------------------------------------------------------
// BN apply + residual, float4 vectorized.
// ---------------------------------------------------------------------------
__global__ void bn_apply_kernel(const float* __restrict__ WY, const float* __restrict__ stats,
                                const float* __restrict__ x,
                                const float* __restrict__ gamma, const float* __restrict__ beta,
                                float* __restrict__ out) {
    int i4 = blockIdx.x * 256 + threadIdx.x;  // < N*C*L/4
    int o = (i4 >> 10) & (CDIM - 1);
    float m = stats[o], is = stats[CDIM + o];
    float ga = gamma[o], be = beta[o];
    float4 w = ((const float4*)WY)[i4];
    float4 xv = ((const float4*)x)[i4];
    float4 r;
    r.x = (w.x - m) * is * ga + be + xv.x;
    r.y = (w.y - m) * is * ga + be + xv.y;
    r.z = (w.z - m) * is * ga + be + xv.z;
    r.w = (w.w - m) * is * ga + be + xv.w;
    ((float4*)out)[i4] = r;
}

// ---------------------------------------------------------------------------
extern "C" void kernel_launch(void* const* d_in, const int* in_sizes, int n_in,
                              void* d_out, int out_size, void* d_ws, size_t ws_size,
                              hipStream_t stream) {
    const float* x   = (const float*)d_in[0];
    const float* gw  = (const float*)d_in[1];
    const float* gb  = (const float*)d_in[2];
    const float* tw  = (const float*)d_in[3];
    const float* tb  = (const float*)d_in[4];
    const float* pw  = (const float*)d_in[5];
    const float* pb  = (const float*)d_in[6];
    const float* zw  = (const float*)d_in[7];
    const float* zb  = (const float*)d_in[8];
    const float* bng = (const float*)d_in[9];
    const float* bnb = (const float*)d_in[10];
    float* out = (float*)d_out;
    float* ws  = (float*)d_ws;

    float* F    = ws + F_OFF;
    u16*   xT   = (u16*)(ws + F_OFF);       // dies before F first written
    float* SP   = ws + SPLIT_OFF;           // split-K partials (after softmax)
    u16*   Pm   = (u16*)(ws + PM_OFF);
    float* WY   = ws + PM_OFF;              // after last Pm read
    u16*   THPH = (u16*)(ws + THPH_OFF);    // (N, L, 512) = [theta | phi]
    u16*   G    = (u16*)(ws + G_OFF);       // (N, CI, L)
    u16*   Y    = (u16*)(ws + Y_OFF);       // (N, L, CI)
    u16*   WB   = (u16*)(ws + WTS_OFF);     // [gw | tw | pw | zw] bf16
    float* BC   = ws + BIAS2_OFF;           // [tb | pb]
    float* ST   = ws + ST_OFF;

    const long LC   = (long)LDIM * CDIM;     // xT batch (u16)
    const long LCI  = (long)LDIM * CIDIM;    // 1,048,576
    const long L512 = (long)LDIM * 512;      // THPH batch (u16)
    const long CL   = (long)CDIM * LDIM;     // WY batch (fp32)

    transpose_x<<<dim3(LDIM / 32, CDIM / 32, NB), dim3(32, 8), 0, stream>>>(x, xT);
    cast_w<<<2048, 256, 0, stream>>>(gw, tw, pw, zw, WB);
    concat_bias<<<2, 256, 0, stream>>>(tb, pb, BC);

    // THPH (N,L,512) = xT(L,C) x [tw;pw](512,C)^T   [bias per-n = BC]
    gemm_nt<2, true><<<dim3(4, 32, NB), 256, 0, stream>>>(
        xT, WB + 131072, THPH, BC, CDIM, CDIM, CDIM, 512, LC, 0, L512);
    // g (N,CI,L) = gw(CI,C) x xT(L,C)^T             [bias per-m]
    gemm_nt<1, true><<<dim3(32, 2, NB), 256, 0, stream>>>(
        WB, xT, G, gb, CDIM, CDIM, CDIM, LDIM, 0, LC, LCI);

    for (int n = 0; n < NB; n++) {
        const u16* TH = THPH + (size_t)n * L512;        // lda = 512
        const u16* PH = THPH + (size_t)n * L512 + 256;  // ldb = 512
        // f (L,L) fp32 = theta x phi^T
        gemm_nt<0, false><<<dim3(32, 32, 1), 256, 0, stream>>>(
            TH, PH, (void*)F, nullptr, CIDIM, 512, 512, LDIM, 0, 0, 0);
        softmax_kernel<<<dim3(LDIM), 256, 0, stream>>>(F, Pm);
        // split-K x8: partial[s] (L,CI) fp32 = Pm[:, s*512:(s+1)*512] x g^T
        gemm_nt<0, false><<<dim3(2, 32, 8), 256, 0, stream>>>(
            Pm, G + (size_t)n * LCI, (void*)SP, nullptr,
            512, LDIM, LDIM, CIDIM, 512, 512, LCI);
        reduce_y<<<dim3(1024), 256, 0, stream>>>(SP, Y + (size_t)n * LCI);
    }

    // WY (N,C,L) fp32 = zw(C,CI) x yT(L,CI)^T  [bias per-m]
    gemm_nt<1, false><<<dim3(32, 4, NB), 256, 0, stream>>>(
        WB + 393216, Y, (void*)WY, zb, CIDIM, CIDIM, CIDIM, LDIM, 0, LCI, CL);

    bn_stats_kernel<<<dim3(CDIM), 256, 0, stream>>>(WY, ST);
    bn_apply_kernel<<<dim3(NB * CDIM * LDIM / 4 / 256), 256, 0, stream>>>(
        WY, ST, x, bng, bnb, out);
}

// Round 5
// 367.865 us; speedup vs baseline: 6.0387x; 1.1929x over previous
//
#include <hip/hip_runtime.h>
#include <hip/hip_bf16.h>

// NLBlockND (embedded non-local block), MI355X/gfx950.
// Round 5: flash-attention fusion. score GEMM + softmax + split-K PV GEMM +
// reduce replaced by one kernel; F/Pm/SP buffers deleted (~256 MB/batch of
// intermediate HBM traffic). Q/K/V tiles in padded LDS, online softmax in
// registers, K/V register-double-buffered across column tiles.
// Shapes: N=4, C=512, CI=256, L=4096.

#define NB    4
#define CDIM  512
#define CIDIM 256
#define LDIM  4096
#define BN_EPS 1e-5f

typedef unsigned short u16;
typedef __attribute__((ext_vector_type(8))) short short8;  // 8 bf16 (4 VGPRs)
typedef __attribute__((ext_vector_type(4))) float f32x4;   // MFMA C/D
typedef __attribute__((ext_vector_type(4))) unsigned short u16x4;

// Workspace (float offsets). xT aliases WY (xT dead before wz writes WY).
#define WY_OFF    0                  // 8,388,608 fp32 (N,C,L); xT bf16 lives here first
#define THPH_OFF  8388608            // 4,194,304 floats (N,L,512 bf16: [theta|phi])
#define G_OFF     12582912           // 2,097,152 floats (g bf16, (N,CI,L))
#define Y_OFF     14680064           // 2,097,152 floats (yT bf16, (N,L,CI))
#define WTS_OFF   16777216           //   262,144 floats = 524,288 bf16 weights
#define BIAS2_OFF 17039360           //       512 floats ([tb|pb])
#define ST_OFF    17039872           //     1,024 floats
// total ~17.04M floats = 68.2 MB

__device__ __forceinline__ u16 f2b(float f) {  // fp32 -> bf16 RNE
    union { float f; unsigned u; } v; v.f = f;
    return (u16)((v.u + 0x7FFFu + ((v.u >> 16) & 1u)) >> 16);
}

__device__ __forceinline__ void gl_lds16(const u16* g, u16* l) {
    __builtin_amdgcn_global_load_lds(
        (const __attribute__((address_space(1))) void*)g,
        (__attribute__((address_space(3))) void*)l, 16, 0, 0);
}

// ---------------------------------------------------------------------------
// x (N,C,L) fp32 -> xT (N,L,C) bf16.  32x32 LDS tiles.
// ---------------------------------------------------------------------------
__global__ void transpose_x(const float* __restrict__ x, u16* __restrict__ xt) {
    __shared__ float tile[32][33];
    int n = blockIdx.z;
    int l0 = blockIdx.x * 32, c0 = blockIdx.y * 32;
    const float* xn = x + (size_t)n * CDIM * LDIM;
    u16* xtn = xt + (size_t)n * LDIM * CDIM;
    int tx = threadIdx.x, ty = threadIdx.y;  // (32, 8)
#pragma unroll
    for (int k = 0; k < 4; k++)
        tile[ty + 8 * k][tx] = xn[(size_t)(c0 + ty + 8 * k) * LDIM + l0 + tx];
    __syncthreads();
#pragma unroll
    for (int k = 0; k < 4; k++)
        xtn[(size_t)(l0 + ty + 8 * k) * CDIM + c0 + tx] = f2b(tile[tx][ty + 8 * k]);
}

// ---------------------------------------------------------------------------
// Cast the 4 weight matrices (each 131072 fp32) to bf16, concatenated.
// ---------------------------------------------------------------------------
__global__ void cast_w(const float* __restrict__ gw, const float* __restrict__ tw,
                       const float* __restrict__ pw, const float* __restrict__ zw,
                       u16* __restrict__ out) {
    int idx = blockIdx.x * 256 + threadIdx.x;
    if (idx >= 4 * 131072) return;
    int seg = idx >> 17, off = idx & 131071;
    const float* s = (seg == 0) ? gw : (seg == 1) ? tw : (seg == 2) ? pw : zw;
    out[idx] = f2b(s[off]);
}

__global__ void concat_bias(const float* __restrict__ tb, const float* __restrict__ pb,
                            float* __restrict__ out) {
    int i = blockIdx.x * 256 + threadIdx.x;
    if (i < 256) out[i] = tb[i];
    else if (i < 512) out[i] = pb[i - 256];
}

// ---------------------------------------------------------------------------
// NT-GEMM: D[m][n] = sum_k A[m][k]*B[n][k] (+bias). 128x128 tile, BK=32,
// 256 threads (4 waves 2x2), 16x16x32 bf16 MFMA, global_load_lds staging.
// ---------------------------------------------------------------------------
template <int BIAS_MODE, bool OUT_BF16>
__global__ __launch_bounds__(256)
void gemm_nt(const u16* __restrict__ A, const u16* __restrict__ B,
             void* __restrict__ Dv, const float* __restrict__ bias,
             int K, int lda, int ldb, int ldd,
             long batchA, long batchB, long batchD) {
    __shared__ __align__(16) u16 As[128 * 32];
    __shared__ __align__(16) u16 Bs[128 * 32];
    int z = blockIdx.z;
    A += (size_t)z * batchA;
    B += (size_t)z * batchB;

    int tid = threadIdx.x, lane = tid & 63, wave = tid >> 6;
    int n0 = blockIdx.x * 128, m0 = blockIdx.y * 128;
    int wr = wave >> 1, wc = wave & 1;

    f32x4 acc[4][4];
#pragma unroll
    for (int i = 0; i < 4; i++)
#pragma unroll
        for (int j = 0; j < 4; j++) acc[i][j] = (f32x4){0.f, 0.f, 0.f, 0.f};

    int sr = wave * 16 + (lane >> 2);
    int sk = (lane & 3) * 8;
    const u16* Ag0 = A + (size_t)(m0 + sr) * lda + sk;
    const u16* Ag1 = A + (size_t)(m0 + 64 + sr) * lda + sk;
    const u16* Bg0 = B + (size_t)(n0 + sr) * ldb + sk;
    const u16* Bg1 = B + (size_t)(n0 + 64 + sr) * ldb + sk;
    u16* Al0 = &As[(wave * 16) * 32];
    u16* Al1 = &As[(64 + wave * 16) * 32];
    u16* Bl0 = &Bs[(wave * 16) * 32];
    u16* Bl1 = &Bs[(64 + wave * 16) * 32];

    int koff = (lane >> 4) * 8;
    int ra = (wr * 64 + (lane & 15)) * 32 + koff;
    int rb = (wc * 64 + (lane & 15)) * 32 + koff;

    for (int k0 = 0; k0 < K; k0 += 32) {
        __syncthreads();
        gl_lds16(Ag0 + k0, Al0);
        gl_lds16(Ag1 + k0, Al1);
        gl_lds16(Bg0 + k0, Bl0);
        gl_lds16(Bg1 + k0, Bl1);
        __syncthreads();

        short8 af[4], bf[4];
#pragma unroll
        for (int mt = 0; mt < 4; mt++) af[mt] = *(const short8*)&As[ra + mt * 16 * 32];
#pragma unroll
        for (int nt = 0; nt < 4; nt++) bf[nt] = *(const short8*)&Bs[rb + nt * 16 * 32];
#pragma unroll
        for (int mt = 0; mt < 4; mt++)
#pragma unroll
            for (int nt = 0; nt < 4; nt++)
                acc[mt][nt] = __builtin_amdgcn_mfma_f32_16x16x32_bf16(
                    af[mt], bf[nt], acc[mt][nt], 0, 0, 0);
    }

#pragma unroll
    for (int mt = 0; mt < 4; mt++) {
        int mg = m0 + wr * 64 + mt * 16 + (lane >> 4) * 4;
#pragma unroll
        for (int nt = 0; nt < 4; nt++) {
            int ng = n0 + wc * 64 + nt * 16 + (lane & 15);
#pragma unroll
            for (int r = 0; r < 4; r++) {
                float v = acc[mt][nt][r];
                if (BIAS_MODE == 1) v += bias[mg + r];
                if (BIAS_MODE == 2) v += bias[ng];
                if (OUT_BF16) {
                    u16* D = (u16*)Dv + (size_t)z * batchD;
                    D[(size_t)(mg + r) * ldd + ng] = f2b(v);
                } else {
                    float* D = (float*)Dv + (size_t)z * batchD;
                    D[(size_t)(mg + r) * ldd + ng] = v;
                }
            }
        }
    }
}

// ---------------------------------------------------------------------------
// Flash attention: per block one 64-row Q-tile of one batch.
//   Q = theta rows (THPH cols 0..255), K = phi rows (cols 256..511),
//   V = g (CI, L) — PV contraction dim (m) is contiguous in g. Output
//   Y (N, L, CI) bf16 = softmax(Q K^T) V^T, online softmax, P in LDS only.
// 256 threads = 4 waves; wave w owns Q rows [w*16, w*16+16).
// grid: 256 blocks, swizzled so one batch maps to 2 XCDs (K/V L2 locality).
// ---------------------------------------------------------------------------
__global__ __launch_bounds__(256)
void flash_attn(const u16* __restrict__ THPH, const u16* __restrict__ G,
                u16* __restrict__ Y) {
    __shared__ __align__(16) u16 Qs[64][264];   // +8 pad: frag reads 2-way max
    __shared__ __align__(16) u16 Ks[64][264];
    __shared__ __align__(16) u16 Vs[256][72];
    __shared__ __align__(16) u16 Ps[4][16][72];

    int b = blockIdx.x;
    int n = (b >> 1) & 3;                       // XCD pair -> batch
    int qt = ((b >> 3) << 1) | (b & 1);
    int q0 = qt * 64;

    const u16* TH = THPH + (size_t)n * LDIM * 512;
    const u16* PH = TH + 256;
    const u16* Gn = G + (size_t)n * LDIM * CIDIM;
    u16* Yn = Y + (size_t)n * LDIM * CIDIM;

    int tid = threadIdx.x, lane = tid & 63, wave = tid >> 6;
    int quad = lane >> 4, lan = lane & 15;

    // ---- load Q tile once ----
#pragma unroll
    for (int i = 0; i < 8; i++) {
        int flat = tid + i * 256;
        int row = flat >> 5, kc = (flat & 31) * 8;
        *(short8*)&Qs[row][kc] = *(const short8*)&TH[(size_t)(q0 + row) * 512 + kc];
    }

    f32x4 o[16];
#pragma unroll
    for (int i = 0; i < 16; i++) o[i] = (f32x4){0.f, 0.f, 0.f, 0.f};
    float mrow[4] = {-1e30f, -1e30f, -1e30f, -1e30f};
    float lrow[4] = {0.f, 0.f, 0.f, 0.f};

    // register double-buffer for K/V tiles
    short8 kreg[8], vreg[8];
#pragma unroll
    for (int i = 0; i < 8; i++) {
        int flat = tid + i * 256;
        int row = flat >> 5, kc = (flat & 31) * 8;
        kreg[i] = *(const short8*)&PH[(size_t)row * 512 + kc];
    }
#pragma unroll
    for (int i = 0; i < 8; i++) {
        int flat = tid + i * 256;
        int c = flat >> 3, mc = (flat & 7) * 8;
        vreg[i] = *(const short8*)&Gn[(size_t)c * LDIM + mc];
    }

#pragma unroll 1
    for (int j = 0; j < 64; j++) {
        __syncthreads();                       // all waves done with prev K/V
#pragma unroll
        for (int i = 0; i < 8; i++) {
            int flat = tid + i * 256;
            int row = flat >> 5, kc = (flat & 31) * 8;
            *(short8*)&Ks[row][kc] = kreg[i];
        }
#pragma unroll
        for (int i = 0; i < 8; i++) {
            int flat = tid + i * 256;
            int c = flat >> 3, mc = (flat & 7) * 8;
            *(short8*)&Vs[c][mc] = vreg[i];
        }
        __syncthreads();

        if (j + 1 < 64) {                      // prefetch next tiles (in flight
            int m1 = (j + 1) * 64;             //  across this iter's compute)
#pragma unroll
            for (int i = 0; i < 8; i++) {
                int flat = tid + i * 256;
                int row = flat >> 5, kc = (flat & 31) * 8;
                kreg[i] = *(const short8*)&PH[(size_t)(m1 + row) * 512 + kc];
            }
#pragma unroll
            for (int i = 0; i < 8; i++) {
                int flat = tid + i * 256;
                int c = flat >> 3, mc = (flat & 7) * 8;
                vreg[i] = *(const short8*)&Gn[(size_t)c * LDIM + m1 + mc];
            }
        }

        // ---- S = Q K^T (wave rows x 64 cols) ----
        f32x4 s[4];
#pragma unroll
        for (int ct = 0; ct < 4; ct++) s[ct] = (f32x4){0.f, 0.f, 0.f, 0.f};
#pragma unroll
        for (int kf = 0; kf < 8; kf++) {
            short8 a = *(const short8*)&Qs[wave * 16 + lan][kf * 32 + quad * 8];
#pragma unroll
            for (int ct = 0; ct < 4; ct++) {
                short8 bb = *(const short8*)&Ks[ct * 16 + lan][kf * 32 + quad * 8];
                s[ct] = __builtin_amdgcn_mfma_f32_16x16x32_bf16(a, bb, s[ct], 0, 0, 0);
            }
        }

        // ---- online softmax (rows = quad*4+r within wave tile) ----
        float alpha[4];
#pragma unroll
        for (int r = 0; r < 4; r++) {
            float mx = fmaxf(fmaxf(s[0][r], s[1][r]), fmaxf(s[2][r], s[3][r]));
#pragma unroll
            for (int msk = 1; msk <= 8; msk <<= 1)
                mx = fmaxf(mx, __shfl_xor(mx, msk, 64));
            float mnew = fmaxf(mrow[r], mx);
            alpha[r] = __expf(mrow[r] - mnew);
            float rs = 0.f;
#pragma unroll
            for (int ct = 0; ct < 4; ct++) {
                float p = __expf(s[ct][r] - mnew);
                rs += p;
                Ps[wave][quad * 4 + r][ct * 16 + lan] = f2b(p);
            }
#pragma unroll
            for (int msk = 1; msk <= 8; msk <<= 1)
                rs += __shfl_xor(rs, msk, 64);
            lrow[r] = lrow[r] * alpha[r] + rs;
            mrow[r] = mnew;
        }
#pragma unroll
        for (int ot = 0; ot < 16; ot++)
#pragma unroll
            for (int r = 0; r < 4; r++) o[ot][r] *= alpha[r];

        // ---- O += P V^T (P wave-private in LDS; in-wave lgkm ordering) ----
#pragma unroll
        for (int kf = 0; kf < 2; kf++) {
            short8 a = *(const short8*)&Ps[wave][lan][kf * 32 + quad * 8];
#pragma unroll
            for (int ot = 0; ot < 16; ot++) {
                short8 bb = *(const short8*)&Vs[ot * 16 + lan][kf * 32 + quad * 8];
                o[ot] = __builtin_amdgcn_mfma_f32_16x16x32_bf16(a, bb, o[ot], 0, 0, 0);
            }
        }
    }

    // ---- epilogue: O /= l, store Y (L, CI) bf16 ----
    float linv[4];
#pragma unroll
    for (int r = 0; r < 4; r++) linv[r] = 1.f / lrow[r];
#pragma unroll
    for (int ot = 0; ot < 16; ot++)
#pragma unroll
        for (int r = 0; r < 4; r++) {
            int row = q0 + wave * 16 + quad * 4 + r;
            Yn[(size_t)row * CIDIM + ot * 16 + lan] = f2b(o[ot][r] * linv[r]);
        }
}

// ---------------------------------------------------------------------------
// BN stats per channel o over (N, L). WY layout (N, C, L) fp32.
// ---------------------------------------------------------------------------
__global__ void bn_stats_kernel(const float* __restrict__ WY, float* __restrict__ stats) {
    int o = blockIdx.x, tid = threadIdx.x, lane = tid & 63, wave = tid >> 6;
    float s = 0.f, s2 = 0.f;
    for (int n = 0; n < NB; n++) {
        const float4* p = (const float4*)(WY + (size_t)(n * CDIM + o) * LDIM);
        for (int i = tid; i < LDIM / 4; i += 256) {
            float4 v = p[i];
            s += v.x + v.y + v.z + v.w;
            s2 += v.x * v.x + v.y * v.y + v.z * v.z + v.w * v.w;
        }
    }
    for (int o2 = 32; o2 > 0; o2 >>= 1) {
        s += __shfl_xor(s, o2, 64);
        s2 += __shfl_xor(s2, o2, 64);
    }
    __shared__ float rs[4], rs2[4];
    if (lane == 0) { rs[wave] = s; rs2[wave] = s2; }
    __syncthreads();
    if (tid == 0) {
        float S = rs[0] + rs[1] + rs[2] + rs[3];
        float S2 = rs2[0] + rs2[1] + rs2[2] + rs2[3];
        const float cnt = (float)(NB * LDIM);
        float mean = S / cnt;
        float var = S2 / cnt - mean * mean;
        stats[o] = mean;
        stats[CDIM + o] = rsqrtf(var + BN_EPS);
    }
}

// ---------------------------------------------------------------------------
// BN apply + residual, float4 vectorized.
// ---------------------------------------------------------------------------
__global__ void bn_apply_kernel(const float* __restrict__ WY, const float* __restrict__ stats,
                                const float* __restrict__ x,
                                const float* __restrict__ gamma, const float* __restrict__ beta,
                                float* __restrict__ out) {
    int i4 = blockIdx.x * 256 + threadIdx.x;  // < N*C*L/4
    int o = (i4 >> 10) & (CDIM - 1);
    float m = stats[o], is = stats[CDIM + o];
    float ga = gamma[o], be = beta[o];
    float4 w = ((const float4*)WY)[i4];
    float4 xv = ((const float4*)x)[i4];
    float4 r;
    r.x = (w.x - m) * is * ga + be + xv.x;
    r.y = (w.y - m) * is * ga + be + xv.y;
    r.z = (w.z - m) * is * ga + be + xv.z;
    r.w = (w.w - m) * is * ga + be + xv.w;
    ((float4*)out)[i4] = r;
}

// ---------------------------------------------------------------------------
extern "C" void kernel_launch(void* const* d_in, const int* in_sizes, int n_in,
                              void* d_out, int out_size, void* d_ws, size_t ws_size,
                              hipStream_t stream) {
    const float* x   = (const float*)d_in[0];
    const float* gw  = (const float*)d_in[1];
    const float* gb  = (const float*)d_in[2];
    const float* tw  = (const float*)d_in[3];
    const float* tb  = (const float*)d_in[4];
    const float* pw  = (const float*)d_in[5];
    const float* pb  = (const float*)d_in[6];
    const float* zw  = (const float*)d_in[7];
    const float* zb  = (const float*)d_in[8];
    const float* bng = (const float*)d_in[9];
    const float* bnb = (const float*)d_in[10];
    float* out = (float*)d_out;
    float* ws  = (float*)d_ws;

    float* WY   = ws + WY_OFF;
    u16*   xT   = (u16*)(ws + WY_OFF);      // dead before wz writes WY
    u16*   THPH = (u16*)(ws + THPH_OFF);    // (N, L, 512) = [theta | phi]
    u16*   G    = (u16*)(ws + G_OFF);       // (N, CI, L)
    u16*   Y    = (u16*)(ws + Y_OFF);       // (N, L, CI)
    u16*   WB   = (u16*)(ws + WTS_OFF);     // [gw | tw | pw | zw] bf16
    float* BC   = ws + BIAS2_OFF;           // [tb | pb]
    float* ST   = ws + ST_OFF;

    const long LC   = (long)LDIM * CDIM;    // xT batch (u16)
    const long LCI  = (long)LDIM * CIDIM;
    const long L512 = (long)LDIM * 512;     // THPH batch (u16)
    const long CL   = (long)CDIM * LDIM;    // WY batch (fp32)

    transpose_x<<<dim3(LDIM / 32, CDIM / 32, NB), dim3(32, 8), 0, stream>>>(x, xT);
    cast_w<<<2048, 256, 0, stream>>>(gw, tw, pw, zw, WB);
    concat_bias<<<2, 256, 0, stream>>>(tb, pb, BC);

    // THPH (N,L,512) = xT(L,C) x [tw;pw](512,C)^T   [bias per-n = BC]
    gemm_nt<2, true><<<dim3(4, 32, NB), 256, 0, stream>>>(
        xT, WB + 131072, THPH, BC, CDIM, CDIM, CDIM, 512, LC, 0, L512);
    // g (N,CI,L) = gw(CI,C) x xT(L,C)^T             [bias per-m]
    gemm_nt<1, true><<<dim3(32, 2, NB), 256, 0, stream>>>(
        WB, xT, G, gb, CDIM, CDIM, CDIM, LDIM, 0, LC, LCI);

    // fused attention: Y (N,L,CI) = softmax(theta phi^T) g^T
    flash_attn<<<dim3(256), 256, 0, stream>>>(THPH, G, Y);

    // WY (N,C,L) fp32 = zw(C,CI) x yT(L,CI)^T  [bias per-m]
    gemm_nt<1, false><<<dim3(32, 4, NB), 256, 0, stream>>>(
        WB + 393216, Y, (void*)WY, zb, CIDIM, CIDIM, CIDIM, LDIM, 0, LCI, CL);

    bn_stats_kernel<<<dim3(CDIM), 256, 0, stream>>>(WY, ST);
    bn_apply_kernel<<<dim3(NB * CDIM * LDIM / 4 / 256), 256, 0, stream>>>(
        WY, ST, x, bng, bnb, out);
}

// Round 6
// 322.566 us; speedup vs baseline: 6.8867x; 1.1404x over previous
//
#include <hip/hip_runtime.h>
#include <hip/hip_bf16.h>

// NLBlockND (embedded non-local block), MI355X/gfx950.
// Round 6: flash-attention v2. Round-5 flash was latency-bound (1 block/CU,
// 4 waves, Occupancy 11%): j-split x2 (grid 512, 2 blocks/CU = 8 waves),
// Q-frags in registers, LDS 113->73 KB, K/V staged via global_load_lds in
// m97-layout chunks. Partial (O,m,l) merged by a small epilogue kernel.
// Shapes: N=4, C=512, CI=256, L=4096.

#define NB    4
#define CDIM  512
#define CIDIM 256
#define LDIM  4096
#define BN_EPS 1e-5f

typedef unsigned short u16;
typedef __attribute__((ext_vector_type(8))) short short8;  // 8 bf16 (4 VGPRs)
typedef __attribute__((ext_vector_type(4))) float f32x4;   // MFMA C/D
typedef __attribute__((ext_vector_type(4))) unsigned short u16x4;

// Workspace (float offsets). WY region hosts, in sequence: xT (bf16, dies
// after projections) -> OP partials (fp32, dies after merge) -> WY (fp32).
#define WY_OFF    0                  // 8,388,608 floats
#define THPH_OFF  8388608            // 4,194,304 floats (N,L,512 bf16 [theta|phi])
#define G_OFF     12582912           // 2,097,152 floats (g bf16, (N,CI,L))
#define Y_OFF     14680064           // 2,097,152 floats (yT bf16, (N,L,CI))
#define WTS_OFF   16777216           //   262,144 floats = 524,288 bf16 weights
#define BIAS2_OFF 17039360           //       512 floats ([tb|pb])
#define ML_OFF    17039872           //    65,536 floats (2 halves x N*L x {m,l})
#define ST_OFF    17105408           //     1,024 floats
// total 17,106,432 floats = 68.4 MB

__device__ __forceinline__ u16 f2b(float f) {  // fp32 -> bf16 RNE
    union { float f; unsigned u; } v; v.f = f;
    return (u16)((v.u + 0x7FFFu + ((v.u >> 16) & 1u)) >> 16);
}

__device__ __forceinline__ void gl_lds16(const u16* g, u16* l) {
    __builtin_amdgcn_global_load_lds(
        (const __attribute__((address_space(1))) void*)g,
        (__attribute__((address_space(3))) void*)l, 16, 0, 0);
}

// ---------------------------------------------------------------------------
// x (N,C,L) fp32 -> xT (N,L,C) bf16.  32x32 LDS tiles.
// ---------------------------------------------------------------------------
__global__ void transpose_x(const float* __restrict__ x, u16* __restrict__ xt) {
    __shared__ float tile[32][33];
    int n = blockIdx.z;
    int l0 = blockIdx.x * 32, c0 = blockIdx.y * 32;
    const float* xn = x + (size_t)n * CDIM * LDIM;
    u16* xtn = xt + (size_t)n * LDIM * CDIM;
    int tx = threadIdx.x, ty = threadIdx.y;  // (32, 8)
#pragma unroll
    for (int k = 0; k < 4; k++)
        tile[ty + 8 * k][tx] = xn[(size_t)(c0 + ty + 8 * k) * LDIM + l0 + tx];
    __syncthreads();
#pragma unroll
    for (int k = 0; k < 4; k++)
        xtn[(size_t)(l0 + ty + 8 * k) * CDIM + c0 + tx] = f2b(tile[tx][ty + 8 * k]);
}

// ---------------------------------------------------------------------------
// Cast the 4 weight matrices (each 131072 fp32) to bf16, concatenated.
// ---------------------------------------------------------------------------
__global__ void cast_w(const float* __restrict__ gw, const float* __restrict__ tw,
                       const float* __restrict__ pw, const float* __restrict__ zw,
                       u16* __restrict__ out) {
    int idx = blockIdx.x * 256 + threadIdx.x;
    if (idx >= 4 * 131072) return;
    int seg = idx >> 17, off = idx & 131071;
    const float* s = (seg == 0) ? gw : (seg == 1) ? tw : (seg == 2) ? pw : zw;
    out[idx] = f2b(s[off]);
}

__global__ void concat_bias(const float* __restrict__ tb, const float* __restrict__ pb,
                            float* __restrict__ out) {
    int i = blockIdx.x * 256 + threadIdx.x;
    if (i < 256) out[i] = tb[i];
    else if (i < 512) out[i] = pb[i - 256];
}

// ---------------------------------------------------------------------------
// NT-GEMM: D[m][n] = sum_k A[m][k]*B[n][k] (+bias). 128x128 tile, BK=32,
// 256 threads (4 waves 2x2), 16x16x32 bf16 MFMA, global_load_lds staging.
// ---------------------------------------------------------------------------
template <int BIAS_MODE, bool OUT_BF16>
__global__ __launch_bounds__(256)
void gemm_nt(const u16* __restrict__ A, const u16* __restrict__ B,
             void* __restrict__ Dv, const float* __restrict__ bias,
             int K, int lda, int ldb, int ldd,
             long batchA, long batchB, long batchD) {
    __shared__ __align__(16) u16 As[128 * 32];
    __shared__ __align__(16) u16 Bs[128 * 32];
    int z = blockIdx.z;
    A += (size_t)z * batchA;
    B += (size_t)z * batchB;

    int tid = threadIdx.x, lane = tid & 63, wave = tid >> 6;
    int n0 = blockIdx.x * 128, m0 = blockIdx.y * 128;
    int wr = wave >> 1, wc = wave & 1;

    f32x4 acc[4][4];
#pragma unroll
    for (int i = 0; i < 4; i++)
#pragma unroll
        for (int j = 0; j < 4; j++) acc[i][j] = (f32x4){0.f, 0.f, 0.f, 0.f};

    int sr = wave * 16 + (lane >> 2);
    int sk = (lane & 3) * 8;
    const u16* Ag0 = A + (size_t)(m0 + sr) * lda + sk;
    const u16* Ag1 = A + (size_t)(m0 + 64 + sr) * lda + sk;
    const u16* Bg0 = B + (size_t)(n0 + sr) * ldb + sk;
    const u16* Bg1 = B + (size_t)(n0 + 64 + sr) * ldb + sk;
    u16* Al0 = &As[(wave * 16) * 32];
    u16* Al1 = &As[(64 + wave * 16) * 32];
    u16* Bl0 = &Bs[(wave * 16) * 32];
    u16* Bl1 = &Bs[(64 + wave * 16) * 32];

    int koff = (lane >> 4) * 8;
    int ra = (wr * 64 + (lane & 15)) * 32 + koff;
    int rb = (wc * 64 + (lane & 15)) * 32 + koff;

    for (int k0 = 0; k0 < K; k0 += 32) {
        __syncthreads();
        gl_lds16(Ag0 + k0, Al0);
        gl_lds16(Ag1 + k0, Al1);
        gl_lds16(Bg0 + k0, Bl0);
        gl_lds16(Bg1 + k0, Bl1);
        __syncthreads();

        short8 af[4], bf[4];
#pragma unroll
        for (int mt = 0; mt < 4; mt++) af[mt] = *(const short8*)&As[ra + mt * 16 * 32];
#pragma unroll
        for (int nt = 0; nt < 4; nt++) bf[nt] = *(const short8*)&Bs[rb + nt * 16 * 32];
#pragma unroll
        for (int mt = 0; mt < 4; mt++)
#pragma unroll
            for (int nt = 0; nt < 4; nt++)
                acc[mt][nt] = __builtin_amdgcn_mfma_f32_16x16x32_bf16(
                    af[mt], bf[nt], acc[mt][nt], 0, 0, 0);
    }

#pragma unroll
    for (int mt = 0; mt < 4; mt++) {
        int mg = m0 + wr * 64 + mt * 16 + (lane >> 4) * 4;
#pragma unroll
        for (int nt = 0; nt < 4; nt++) {
            int ng = n0 + wc * 64 + nt * 16 + (lane & 15);
#pragma unroll
            for (int r = 0; r < 4; r++) {
                float v = acc[mt][nt][r];
                if (BIAS_MODE == 1) v += bias[mg + r];
                if (BIAS_MODE == 2) v += bias[ng];
                if (OUT_BF16) {
                    u16* D = (u16*)Dv + (size_t)z * batchD;
                    D[(size_t)(mg + r) * ldd + ng] = f2b(v);
                } else {
                    float* D = (float*)Dv + (size_t)z * batchD;
                    D[(size_t)(mg + r) * ldd + ng] = v;
                }
            }
        }
    }
}

// ---------------------------------------------------------------------------
// Flash attention v2 (j-split). Block = one 64-row Q-tile x one half of the
// K/V column range (32 of 64 tiles). 256 threads = 4 waves, wave w owns Q
// rows [w*16, w*16+16). Q-frags in registers; K/V staged via global_load_lds
// into 32-u16-stride LDS chunks (m97 bank pattern). Emits unnormalized
// partial O (fp32) + per-row (m, l); merge_y combines the two halves.
// grid: 512 blocks; b&3 = batch (fixed per XCD for K/V L2 locality).
// ---------------------------------------------------------------------------
__global__ __launch_bounds__(256)
void flash_attn(const u16* __restrict__ THPH, const u16* __restrict__ G,
                float* __restrict__ OP, float* __restrict__ ML) {
    __shared__ __align__(16) u16 Ks[8 * 2048];   // [kf][64 j-rows][32 k]  32 KB
    __shared__ __align__(16) u16 Vs[2 * 8192];   // [jf][256 ci][32 j]     32 KB
    __shared__ __align__(16) u16 Ps[4][16][72];  //                        9 KB

    int b = blockIdx.x;
    int n = b & 3;                 // XCD b%8 -> batches n, n+4 both = n mod 4
    int m = b >> 2;                // 0..127
    int qt = m >> 1;               // 64 Q-tiles
    int jh = m & 1;                // K/V half
    int q0 = qt * 64;

    const u16* TH = THPH + (size_t)n * LDIM * 512;
    const u16* PH = TH + 256;
    const u16* Gn = G + (size_t)n * LDIM * CIDIM;
    float* OPh = OP + ((size_t)jh * NB + n) * LDIM * CIDIM;
    float* MLh = ML + ((size_t)jh * NB + n) * LDIM * 2;

    int tid = threadIdx.x, lane = tid & 63, wave = tid >> 6;
    int quad = lane >> 4, lan = lane & 15;
    int srow = lane >> 2, skp = (lane & 3) * 8;   // staging decomposition

    // ---- Q fragments, loop-invariant, straight from global ----
    short8 qf[8];
    {
        const u16* qb = TH + (size_t)(q0 + wave * 16 + lan) * 512 + quad * 8;
#pragma unroll
        for (int kf = 0; kf < 8; kf++) qf[kf] = *(const short8*)(qb + kf * 32);
    }

    f32x4 o[16];
#pragma unroll
    for (int i = 0; i < 16; i++) o[i] = (f32x4){0.f, 0.f, 0.f, 0.f};
    float mrow[4] = {-1e30f, -1e30f, -1e30f, -1e30f};
    float lrow[4] = {0.f, 0.f, 0.f, 0.f};

#pragma unroll 1
    for (int jt = 0; jt < 32; jt++) {
        int j0 = (jh * 32 + jt) * 64;
        __syncthreads();
        // stage K tile: 8 chunks of (64 rows x 32 k), wave fills its quarter
#pragma unroll
        for (int kf = 0; kf < 8; kf++)
            gl_lds16(PH + (size_t)(j0 + wave * 16 + srow) * 512 + kf * 32 + skp,
                     &Ks[kf * 2048 + wave * 512]);
        // stage V tile: 2 chunks of (256 ci x 32 j), 4 rounds each
#pragma unroll
        for (int jf = 0; jf < 2; jf++)
#pragma unroll
            for (int r = 0; r < 4; r++)
                gl_lds16(Gn + (size_t)(r * 64 + wave * 16 + srow) * LDIM
                            + j0 + jf * 32 + skp,
                         &Vs[jf * 8192 + r * 2048 + wave * 512]);
        __syncthreads();

        // ---- S = Q K^T (16 rows x 64 cols per wave) ----
        f32x4 s[4];
#pragma unroll
        for (int ct = 0; ct < 4; ct++) s[ct] = (f32x4){0.f, 0.f, 0.f, 0.f};
#pragma unroll
        for (int kf = 0; kf < 8; kf++)
#pragma unroll
            for (int ct = 0; ct < 4; ct++) {
                short8 bb = *(const short8*)&Ks[kf * 2048 + (ct * 16 + lan) * 32 + quad * 8];
                s[ct] = __builtin_amdgcn_mfma_f32_16x16x32_bf16(qf[kf], bb, s[ct], 0, 0, 0);
            }

        // ---- online softmax ----
        float alpha[4];
#pragma unroll
        for (int r = 0; r < 4; r++) {
            float mx = fmaxf(fmaxf(s[0][r], s[1][r]), fmaxf(s[2][r], s[3][r]));
#pragma unroll
            for (int msk = 1; msk <= 8; msk <<= 1)
                mx = fmaxf(mx, __shfl_xor(mx, msk, 64));
            float mnew = fmaxf(mrow[r], mx);
            alpha[r] = __expf(mrow[r] - mnew);
            float rs = 0.f;
#pragma unroll
            for (int ct = 0; ct < 4; ct++) {
                float p = __expf(s[ct][r] - mnew);
                rs += p;
                Ps[wave][quad * 4 + r][ct * 16 + lan] = f2b(p);
            }
#pragma unroll
            for (int msk = 1; msk <= 8; msk <<= 1)
                rs += __shfl_xor(rs, msk, 64);
            lrow[r] = lrow[r] * alpha[r] + rs;
            mrow[r] = mnew;
        }
#pragma unroll
        for (int ot = 0; ot < 16; ot++)
#pragma unroll
            for (int r = 0; r < 4; r++) o[ot][r] *= alpha[r];

        // ---- O += P V^T (P wave-private; in-wave lgkm ordering) ----
#pragma unroll
        for (int kf2 = 0; kf2 < 2; kf2++) {
            short8 a = *(const short8*)&Ps[wave][lan][kf2 * 32 + quad * 8];
#pragma unroll
            for (int ot = 0; ot < 16; ot++) {
                short8 bb = *(const short8*)&Vs[kf2 * 8192 + (ot * 16 + lan) * 32 + quad * 8];
                o[ot] = __builtin_amdgcn_mfma_f32_16x16x32_bf16(a, bb, o[ot], 0, 0, 0);
            }
        }
    }

    // ---- epilogue: unnormalized partial O + (m, l) per row ----
#pragma unroll
    for (int r = 0; r < 4; r++) {
        int row = q0 + wave * 16 + quad * 4 + r;
        if (lan == 0) {
            MLh[row * 2] = mrow[r];
            MLh[row * 2 + 1] = lrow[r];
        }
#pragma unroll
        for (int ot = 0; ot < 16; ot++)
            OPh[(size_t)row * CIDIM + ot * 16 + lan] = o[ot][r];
    }
}

// ---------------------------------------------------------------------------
// Merge the two j-halves: Y = (Oa*e^(ma-M) + Ob*e^(mb-M)) / (la*e^.. + lb*e^..)
// ---------------------------------------------------------------------------
__global__ void merge_y(const float* __restrict__ OP, const float* __restrict__ ML,
                        u16* __restrict__ Y) {
    const size_t HALF = (size_t)NB * LDIM * CIDIM;
    const int HALF_ML = NB * LDIM * 2;
    int i4 = blockIdx.x * 256 + threadIdx.x;     // over N*L*CI/4
    int row = i4 >> 6;                           // n*L + l
    float ma = ML[row * 2], la = ML[row * 2 + 1];
    float mb = ML[HALF_ML + row * 2], lb = ML[HALF_ML + row * 2 + 1];
    float M = fmaxf(ma, mb);
    float ea = __expf(ma - M), eb = __expf(mb - M);
    float inv = 1.f / (la * ea + lb * eb);
    float4 oa = ((const float4*)OP)[i4];
    float4 ob = ((const float4*)(OP + HALF))[i4];
    u16x4 y;
    y.x = f2b((oa.x * ea + ob.x * eb) * inv);
    y.y = f2b((oa.y * ea + ob.y * eb) * inv);
    y.z = f2b((oa.z * ea + ob.z * eb) * inv);
    y.w = f2b((oa.w * ea + ob.w * eb) * inv);
    ((u16x4*)Y)[i4] = y;
}

// ---------------------------------------------------------------------------
// BN stats per channel o over (N, L). WY layout (N, C, L) fp32.
// ---------------------------------------------------------------------------
__global__ void bn_stats_kernel(const float* __restrict__ WY, float* __restrict__ stats) {
    int o = blockIdx.x, tid = threadIdx.x, lane = tid & 63, wave = tid >> 6;
    float s = 0.f, s2 = 0.f;
    for (int n = 0; n < NB; n++) {
        const float4* p = (const float4*)(WY + (size_t)(n * CDIM + o) * LDIM);
        for (int i = tid; i < LDIM / 4; i += 256) {
            float4 v = p[i];
            s += v.x + v.y + v.z + v.w;
            s2 += v.x * v.x + v.y * v.y + v.z * v.z + v.w * v.w;
        }
    }
    for (int o2 = 32; o2 > 0; o2 >>= 1) {
        s += __shfl_xor(s, o2, 64);
        s2 += __shfl_xor(s2, o2, 64);
    }
    __shared__ float rs[4], rs2[4];
    if (lane == 0) { rs[wave] = s; rs2[wave] = s2; }
    __syncthreads();
    if (tid == 0) {
        float S = rs[0] + rs[1] + rs[2] + rs[3];
        float S2 = rs2[0] + rs2[1] + rs2[2] + rs2[3];
        const float cnt = (float)(NB * LDIM);
        float mean = S / cnt;
        float var = S2 / cnt - mean * mean;
        stats[o] = mean;
        stats[CDIM + o] = rsqrtf(var + BN_EPS);
    }
}

// ---------------------------------------------------------------------------
// BN apply + residual, float4 vectorized.
// ---------------------------------------------------------------------------
__global__ void bn_apply_kernel(const float* __restrict__ WY, const float* __restrict__ stats,
                                const float* __restrict__ x,
                                const float* __restrict__ gamma, const float* __restrict__ beta,
                                float* __restrict__ out) {
    int i4 = blockIdx.x * 256 + threadIdx.x;  // < N*C*L/4
    int o = (i4 >> 10) & (CDIM - 1);
    float m = stats[o], is = stats[CDIM + o];
    float ga = gamma[o], be = beta[o];
    float4 w = ((const float4*)WY)[i4];
    float4 xv = ((const float4*)x)[i4];
    float4 r;
    r.x = (w.x - m) * is * ga + be + xv.x;
    r.y = (w.y - m) * is * ga + be + xv.y;
    r.z = (w.z - m) * is * ga + be + xv.z;
    r.w = (w.w - m) * is * ga + be + xv.w;
    ((float4*)out)[i4] = r;
}

// ---------------------------------------------------------------------------
extern "C" void kernel_launch(void* const* d_in, const int* in_sizes, int n_in,
                              void* d_out, int out_size, void* d_ws, size_t ws_size,
                              hipStream_t stream) {
    const float* x   = (const float*)d_in[0];
    const float* gw  = (const float*)d_in[1];
    const float* gb  = (const float*)d_in[2];
    const float* tw  = (const float*)d_in[3];
    const float* tb  = (const float*)d_in[4];
    const float* pw  = (const float*)d_in[5];
    const float* pb  = (const float*)d_in[6];
    const float* zw  = (const float*)d_in[7];
    const float* zb  = (const float*)d_in[8];
    const float* bng = (const float*)d_in[9];
    const float* bnb = (const float*)d_in[10];
    float* out = (float*)d_out;
    float* ws  = (float*)d_ws;

    float* WY   = ws + WY_OFF;
    u16*   xT   = (u16*)(ws + WY_OFF);      // dies before flash writes OP
    float* OP   = ws + WY_OFF;              // partials; die before wz writes WY
    u16*   THPH = (u16*)(ws + THPH_OFF);    // (N, L, 512) = [theta | phi]
    u16*   G    = (u16*)(ws + G_OFF);       // (N, CI, L)
    u16*   Y    = (u16*)(ws + Y_OFF);       // (N, L, CI)
    u16*   WB   = (u16*)(ws + WTS_OFF);     // [gw | tw | pw | zw] bf16
    float* BC   = ws + BIAS2_OFF;           // [tb | pb]
    float* ML   = ws + ML_OFF;
    float* ST   = ws + ST_OFF;

    const long LC   = (long)LDIM * CDIM;    // xT batch (u16)
    const long LCI  = (long)LDIM * CIDIM;
    const long L512 = (long)LDIM * 512;     // THPH batch (u16)
    const long CL   = (long)CDIM * LDIM;    // WY batch (fp32)

    transpose_x<<<dim3(LDIM / 32, CDIM / 32, NB), dim3(32, 8), 0, stream>>>(x, xT);
    cast_w<<<2048, 256, 0, stream>>>(gw, tw, pw, zw, WB);
    concat_bias<<<2, 256, 0, stream>>>(tb, pb, BC);

    // THPH (N,L,512) = xT(L,C) x [tw;pw](512,C)^T   [bias per-n = BC]
    gemm_nt<2, true><<<dim3(4, 32, NB), 256, 0, stream>>>(
        xT, WB + 131072, THPH, BC, CDIM, CDIM, CDIM, 512, LC, 0, L512);
    // g (N,CI,L) = gw(CI,C) x xT(L,C)^T             [bias per-m]
    gemm_nt<1, true><<<dim3(32, 2, NB), 256, 0, stream>>>(
        WB, xT, G, gb, CDIM, CDIM, CDIM, LDIM, 0, LC, LCI);

    // fused attention (j-split x2) + merge
    flash_attn<<<dim3(512), 256, 0, stream>>>(THPH, G, OP, ML);
    merge_y<<<dim3(NB * LDIM * CIDIM / 4 / 256), 256, 0, stream>>>(OP, ML, Y);

    // WY (N,C,L) fp32 = zw(C,CI) x yT(L,CI)^T  [bias per-m]
    gemm_nt<1, false><<<dim3(32, 4, NB), 256, 0, stream>>>(
        WB + 393216, Y, (void*)WY, zb, CIDIM, CIDIM, CIDIM, LDIM, 0, LCI, CL);

    bn_stats_kernel<<<dim3(CDIM), 256, 0, stream>>>(WY, ST);
    bn_apply_kernel<<<dim3(NB * CDIM * LDIM / 4 / 256), 256, 0, stream>>>(
        WY, ST, x, bng, bnb, out);
}